// Round 13
// baseline (236.391 us; speedup 1.0000x reference)
//
#include <hip/hip_runtime.h>

// BitLinear: LN (no affine) -> global absmax int8 quant -> q @ sign(W-mean(W))^T
//   -> * (maxval/128 * mean|W|) + bias
// x: [4,2048,2048] f32 -> M=8192,K=2048 ; W: [8192,2048] -> N=8192 ; out f32 [8192,8192]

using i32x4 = __attribute__((ext_vector_type(4))) int;
using i32x16 = __attribute__((ext_vector_type(16))) int;

typedef const __attribute__((address_space(1))) void cg_void;
typedef __attribute__((address_space(3))) void lds_void;

#define K_DIM 2048
#define N_DIM 8192
#define M_DIM 8192
#define NELEM_W 16777216   // 8192*2048

// ws layout: scal@0 ([0]=absmax f32, [1]=wmean, [2]=beta); part@1024; mu@32768;
//            rstd@65536; rowmax@98304; q@131072; wq@131072+16M

// ---- fused pass1: W sum/abs-sum partials (blocks 0..1023) + LN stats (1024..9215) ----
__global__ __launch_bounds__(256) void pass1(const float* __restrict__ x,
                                             const float4* __restrict__ w4,
                                             float* __restrict__ mu_arr,
                                             float* __restrict__ rstd_arr,
                                             float* __restrict__ rowmax,
                                             double2* __restrict__ part) {
    __shared__ double sbd[8];
    __shared__ float sb1[4];
    __shared__ float sb2[8];
    const int bid = blockIdx.x, t = threadIdx.x;
    const int lane = t & 63, wv = t >> 6;
    if (bid < 1024) {
        double s = 0.0, a = 0.0;
        for (int i = bid * 256 + t; i < NELEM_W / 4; i += 1024 * 256) {
            float4 v = w4[i];
            s += (double)v.x + (double)v.y + (double)v.z + (double)v.w;
            a += fabs((double)v.x) + fabs((double)v.y) + fabs((double)v.z) + fabs((double)v.w);
        }
        for (int o = 32; o; o >>= 1) { s += __shfl_xor(s, o); a += __shfl_xor(a, o); }
        if (lane == 0) { sbd[wv] = s; sbd[4 + wv] = a; }
        __syncthreads();
        if (t == 0) {
            double2 r;
            r.x = sbd[0] + sbd[1] + sbd[2] + sbd[3];
            r.y = sbd[4] + sbd[5] + sbd[6] + sbd[7];
            part[bid] = r;
        }
    } else {
        const int row = bid - 1024;
        const float4* xr = (const float4*)x + (size_t)row * 512;
        float4 v0 = xr[t], v1 = xr[t + 256];
        float s = v0.x + v0.y + v0.z + v0.w + v1.x + v1.y + v1.z + v1.w;
        for (int o = 32; o; o >>= 1) s += __shfl_xor(s, o);
        if (lane == 0) sb1[wv] = s;
        __syncthreads();
        float mu = (sb1[0] + sb1[1] + sb1[2] + sb1[3]) * (1.0f / 2048.0f);
        float ssq = 0.f, md = 0.f, d;
        d = v0.x - mu; ssq += d * d; md = fmaxf(md, fabsf(d));
        d = v0.y - mu; ssq += d * d; md = fmaxf(md, fabsf(d));
        d = v0.z - mu; ssq += d * d; md = fmaxf(md, fabsf(d));
        d = v0.w - mu; ssq += d * d; md = fmaxf(md, fabsf(d));
        d = v1.x - mu; ssq += d * d; md = fmaxf(md, fabsf(d));
        d = v1.y - mu; ssq += d * d; md = fmaxf(md, fabsf(d));
        d = v1.z - mu; ssq += d * d; md = fmaxf(md, fabsf(d));
        d = v1.w - mu; ssq += d * d; md = fmaxf(md, fabsf(d));
        for (int o = 32; o; o >>= 1) {
            ssq += __shfl_xor(ssq, o);
            md = fmaxf(md, __shfl_xor(md, o));
        }
        if (lane == 0) { sb2[wv] = ssq; sb2[4 + wv] = md; }
        __syncthreads();
        if (t == 0) {
            float var = (sb2[0] + sb2[1] + sb2[2] + sb2[3]) * (1.0f / 2048.0f);
            float rstd = 1.0f / sqrtf(var + 1e-5f);
            mu_arr[row] = mu;
            rstd_arr[row] = rstd;
            rowmax[row] = fmaxf(fmaxf(sb2[4], sb2[5]), fmaxf(sb2[6], sb2[7])) * rstd;
        }
    }
}

// ---- wred2: finalize wmean/beta + global absmax ----
__global__ __launch_bounds__(256) void wred2(const double2* __restrict__ part,
                                             const float* __restrict__ rowmax,
                                             unsigned* __restrict__ scal) {
    double s = 0.0, a = 0.0;
    float m = 0.f;
    const int t = threadIdx.x, lane = t & 63, wv = t >> 6;
    for (int i = t; i < 1024; i += 256) { double2 p = part[i]; s += p.x; a += p.y; }
    for (int i = t; i < 8192; i += 256) m = fmaxf(m, rowmax[i]);
    for (int o = 32; o; o >>= 1) {
        s += __shfl_xor(s, o); a += __shfl_xor(a, o);
        m = fmaxf(m, __shfl_xor(m, o));
    }
    __shared__ double sbd[8];
    __shared__ float sbm[4];
    if (lane == 0) { sbd[wv] = s; sbd[4 + wv] = a; sbm[wv] = m; }
    __syncthreads();
    if (t == 0) {
        double st = sbd[0] + sbd[1] + sbd[2] + sbd[3];
        double at = sbd[4] + sbd[5] + sbd[6] + sbd[7];
        ((float*)scal)[0] = fmaxf(fmaxf(sbm[0], sbm[1]), fmaxf(sbm[2], sbm[3]));
        ((float*)scal)[1] = (float)(st / (double)NELEM_W);  // wmean
        ((float*)scal)[2] = (float)(at / (double)NELEM_W);  // beta
    }
}

// ---- fused pass2: quant_w (blocks 0..1023) + quant_x (1024..9215) ----
__device__ __forceinline__ int sgn8(float d) { return (d > 0.f) ? 1 : ((d < 0.f) ? -1 : 0); }

__global__ __launch_bounds__(256) void pass2(const float* __restrict__ x,
                                             const float4* __restrict__ w4,
                                             const float* __restrict__ mu_arr,
                                             const float* __restrict__ rstd_arr,
                                             const unsigned* __restrict__ scal,
                                             signed char* __restrict__ q,
                                             int4* __restrict__ wq4) {
    const int bid = blockIdx.x, t = threadIdx.x;
    if (bid < 1024) {
        float wm = ((const float*)scal)[1];
        for (int i = bid * 256 + t; i < NELEM_W / 16; i += 1024 * 256) {
            int words[4];
            #pragma unroll
            for (int jj = 0; jj < 4; ++jj) {
                float4 v = w4[i * 4 + jj];
                int b0 = sgn8(v.x - wm) & 255, b1 = sgn8(v.y - wm) & 255;
                int b2 = sgn8(v.z - wm) & 255, b3 = sgn8(v.w - wm) & 255;
                words[jj] = b0 | (b1 << 8) | (b2 << 16) | (b3 << 24);
            }
            wq4[i] = make_int4(words[0], words[1], words[2], words[3]);
        }
    } else {
        const int row = bid - 1024;
        float mu = mu_arr[row], rstd = rstd_arr[row];
        float s = 128.0f / ((const float*)scal)[0];
        const float4* xr = (const float4*)x + (size_t)row * 512;
        float4 v0 = xr[2 * t], v1 = xr[2 * t + 1];
        float xs[8] = {v0.x, v0.y, v0.z, v0.w, v1.x, v1.y, v1.z, v1.w};
        int b[8];
        #pragma unroll
        for (int j = 0; j < 8; ++j) {
            float norm = (xs[j] - mu) * rstd;
            int qi = (int)rintf(norm * s);   // half-even == jnp.round; +128 wraps via &255
            b[j] = qi & 255;
        }
        int w0 = b[0] | (b[1] << 8) | (b[2] << 16) | (b[3] << 24);
        int w1 = b[4] | (b[5] << 8) | (b[6] << 16) | (b[7] << 24);
        ((int2*)(q + (size_t)row * 2048))[t] = make_int2(w0, w1);
    }
}

// ---- int8 GEMM v13: 256x256 tile, BK=64, FULL B staging (r12 bug fixed) ----
// 8 waves (2Mx4N), wave 128x64 = 4x2 of 32x32x32 (acc 128 VGPR), 64KB LDS dbuf,
// 1 block/CU. Per buffer: A 16KB [0,16K) + B 16KB [16K,32K); each wave stages rows
// w*32..w*32+31 of BOTH A and B (2 chunks each, 4 loads/thread, vmcnt(4)).
// r6 involution swizzle on 64B rows (conflict tax measured non-binding, r10).
// Rationale: maximize FLOP per barrier window (8.4 MFLOP/window-pair, 2x r6) under
// the measured ~850cyc/window invariant across r2-r11.
#define LD16(p) (*(const i32x4*)(p))
#define TB 32768   // per tile buffer: A 16K + B 16K

#define STAGE(koff, sbase)                                                                  \
    do {                                                                                    \
        __builtin_amdgcn_global_load_lds((cg_void*)(gA + (koff)),                           \
            (lds_void*)(lds + (sbase) + w * 2048), 16, 0, 0);                               \
        __builtin_amdgcn_global_load_lds((cg_void*)(gA + 16 * K_DIM + (koff)),              \
            (lds_void*)(lds + (sbase) + w * 2048 + 1024), 16, 0, 0);                        \
        __builtin_amdgcn_global_load_lds((cg_void*)(gB + (koff)),                           \
            (lds_void*)(lds + (sbase) + 16384 + w * 2048), 16, 0, 0);                       \
        __builtin_amdgcn_global_load_lds((cg_void*)(gB + 16 * K_DIM + (koff)),              \
            (lds_void*)(lds + (sbase) + 16384 + w * 2048 + 1024), 16, 0, 0);                \
    } while (0)

__global__ __launch_bounds__(512, 2) void gemm_i8(const signed char* __restrict__ A,
                                                  const signed char* __restrict__ B,
                                                  const float* __restrict__ bias,
                                                  const unsigned* __restrict__ scal,
                                                  float* __restrict__ C) {
    __shared__ alignas(16) char lds[65536];    // 2 x 32KB
    const int t = threadIdx.x, w = t >> 6, lane = t & 63;

    // grid 1024 = 8 XCD x (4 m-panels x 32 n); A panel (512 KB) stays L2-hot per XCD.
    const int wg = blockIdx.x;
    const int xcd = wg & 7, idx = wg >> 3;
    const int bm = (xcd * 4 + (idx >> 5)) * 256;
    const int bn = (idx & 31) * 256;

    const int wr = w >> 2, wc = w & 3;         // wave grid 2M x 4N, wave tile 128x64
    const int r32 = lane & 31, hi = lane >> 5; // 32x32 fragment coords

    // staging: thread stages 16B per load; LDS dest wave-linear (1KB chunks of 16 rows);
    // global source col carries the involution col ^ (((lane>>3)&3)<<4)
    const int srow = lane >> 2;
    const int scol = ((lane & 3) ^ ((lane >> 3) & 3)) << 4;
    const signed char* gA = A + (size_t)(bm + w * 32 + srow) * K_DIM + scol;
    const signed char* gB = B + (size_t)(bn + w * 32 + srow) * K_DIM + scol;

    // fragment reads: A row = wr*128 + mb*32 + r32 (<256); B row = wc*64 + nb*32 + r32 (<256)
    const char* aBase = lds + (wr * 128 + r32) * 64;
    const char* bBase = lds + 16384 + (wc * 64 + r32) * 64;
    const int swz = ((r32 >> 1) & 3) << 4;
    const int sw0 = (hi * 16) ^ swz;           // kstep 0
    const int sw1 = (32 + hi * 16) ^ swz;      // kstep 1

    const float scale = (((const float*)scal)[0] * (1.0f / 128.0f)) * ((const float*)scal)[2];

    i32x16 acc[4][2] = {};
    i32x4 a0[4], a1[4], b0[2], b1[2];

    STAGE(0, 0);   // prologue: tile 0 -> buf0 (4 loads/thread in flight)

    for (int kt = 0; kt < 32; ++kt) {
        const int c = (kt & 1) * TB;
        if (kt < 31) {
            STAGE((kt + 1) * 64, ((kt + 1) & 1) * TB);
            asm volatile("s_waitcnt vmcnt(4)" ::: "memory");  // this tile's 4 landed
        } else {
            asm volatile("s_waitcnt vmcnt(0)" ::: "memory");
        }
        __builtin_amdgcn_s_barrier();          // buf c ready

        // reads lead MFMAs: ks0 fragments, ks1 issues while ks0 computes
        #pragma unroll
        for (int mb = 0; mb < 4; ++mb) a0[mb] = LD16(aBase + c + mb * 2048 + sw0);
        #pragma unroll
        for (int nb = 0; nb < 2; ++nb) b0[nb] = LD16(bBase + c + nb * 2048 + sw0);
        #pragma unroll
        for (int mb = 0; mb < 4; ++mb) a1[mb] = LD16(aBase + c + mb * 2048 + sw1);
        #pragma unroll
        for (int nb = 0; nb < 2; ++nb) b1[nb] = LD16(bBase + c + nb * 2048 + sw1);
        __builtin_amdgcn_s_setprio(1);
        #pragma unroll
        for (int mb = 0; mb < 4; ++mb)
            #pragma unroll
            for (int nb = 0; nb < 2; ++nb)
                acc[mb][nb] = __builtin_amdgcn_mfma_i32_32x32x32_i8(a0[mb], b0[nb],
                                                                    acc[mb][nb], 0, 0, 0);
        #pragma unroll
        for (int mb = 0; mb < 4; ++mb)
            #pragma unroll
            for (int nb = 0; nb < 2; ++nb)
                acc[mb][nb] = __builtin_amdgcn_mfma_i32_32x32x32_i8(a1[mb], b1[nb],
                                                                    acc[mb][nb], 0, 0, 0);
        __builtin_amdgcn_s_setprio(0);
        __builtin_amdgcn_s_barrier();          // all waves done reading buf c
    }

    const int colbase = bn + wc * 64;
    float bi[2];
    #pragma unroll
    for (int nb = 0; nb < 2; ++nb) bi[nb] = bias[colbase + nb * 32 + r32];
    #pragma unroll
    for (int mb = 0; mb < 4; ++mb) {
        #pragma unroll
        for (int nb = 0; nb < 2; ++nb) {
            #pragma unroll
            for (int r = 0; r < 16; ++r) {
                // C/D 32x32: col = lane&31, row = (r&3) + 8*(r>>2) + 4*(lane>>5)
                int row = bm + wr * 128 + mb * 32 + (r & 3) + 8 * (r >> 2) + 4 * hi;
                int col = colbase + nb * 32 + r32;
                C[(size_t)row * N_DIM + col] = (float)acc[mb][nb][r] * scale + bi[nb];
            }
        }
    }
}

extern "C" void kernel_launch(void* const* d_in, const int* in_sizes, int n_in,
                              void* d_out, int out_size, void* d_ws, size_t ws_size,
                              hipStream_t stream) {
    const float* x = (const float*)d_in[0];
    const float* wts = (const float*)d_in[1];
    const float* bias = (const float*)d_in[2];
    float* out = (float*)d_out;

    char* ws = (char*)d_ws;
    unsigned* scal = (unsigned*)ws;                       // 64 B
    double2* part = (double2*)(ws + 1024);                // 16 KB
    float* mu = (float*)(ws + 32768);                     // 32 KB
    float* rstd = (float*)(ws + 65536);                   // 32 KB
    float* rowmax = (float*)(ws + 98304);                 // 32 KB
    signed char* q = (signed char*)(ws + 131072);         // 16 MB
    signed char* wq = (signed char*)(ws + 131072 + 16777216);  // 16 MB

    hipLaunchKernelGGL(pass1, dim3(9216), dim3(256), 0, stream,
                       x, (const float4*)wts, mu, rstd, rowmax, part);
    hipLaunchKernelGGL(wred2, dim3(1), dim3(256), 0, stream, part, rowmax, scal);
    hipLaunchKernelGGL(pass2, dim3(9216), dim3(256), 0, stream,
                       x, (const float4*)wts, mu, rstd, scal, q, (int4*)wq);
    hipLaunchKernelGGL(gemm_i8, dim3(1024), dim3(512), 0, stream,
                       q, wq, bias, scal, out);
}

// Round 14
// 232.379 us; speedup vs baseline: 1.0173x; 1.0173x over previous
//
#include <hip/hip_runtime.h>

// BitLinear: LN (no affine) -> global absmax int8 quant -> q @ sign(W-mean(W))^T
//   -> * (maxval/128 * mean|W|) + bias
// x: [4,2048,2048] f32 -> M=8192,K=2048 ; W: [8192,2048] -> N=8192 ; out f32 [8192,8192]

using i32x4 = __attribute__((ext_vector_type(4))) int;

typedef const __attribute__((address_space(1))) void cg_void;
typedef __attribute__((address_space(3))) void lds_void;

#define K_DIM 2048
#define N_DIM 8192
#define M_DIM 8192
#define NELEM_W 16777216   // 8192*2048

// ws layout: scal@0 ([0]=absmax f32, [1]=wmean, [2]=beta); part@1024; mu@32768;
//            rstd@65536; rowmax@98304; q@131072; wq@131072+16M

// ---- fused pass1: W sum/abs-sum partials (blocks 0..1023) + LN stats (1024..9215) ----
__global__ __launch_bounds__(256) void pass1(const float* __restrict__ x,
                                             const float4* __restrict__ w4,
                                             float* __restrict__ mu_arr,
                                             float* __restrict__ rstd_arr,
                                             float* __restrict__ rowmax,
                                             double2* __restrict__ part) {
    __shared__ double sbd[8];
    __shared__ float sb1[4];
    __shared__ float sb2[8];
    const int bid = blockIdx.x, t = threadIdx.x;
    const int lane = t & 63, wv = t >> 6;
    if (bid < 1024) {
        double s = 0.0, a = 0.0;
        for (int i = bid * 256 + t; i < NELEM_W / 4; i += 1024 * 256) {
            float4 v = w4[i];
            s += (double)v.x + (double)v.y + (double)v.z + (double)v.w;
            a += fabs((double)v.x) + fabs((double)v.y) + fabs((double)v.z) + fabs((double)v.w);
        }
        for (int o = 32; o; o >>= 1) { s += __shfl_xor(s, o); a += __shfl_xor(a, o); }
        if (lane == 0) { sbd[wv] = s; sbd[4 + wv] = a; }
        __syncthreads();
        if (t == 0) {
            double2 r;
            r.x = sbd[0] + sbd[1] + sbd[2] + sbd[3];
            r.y = sbd[4] + sbd[5] + sbd[6] + sbd[7];
            part[bid] = r;
        }
    } else {
        const int row = bid - 1024;
        const float4* xr = (const float4*)x + (size_t)row * 512;
        float4 v0 = xr[t], v1 = xr[t + 256];
        float s = v0.x + v0.y + v0.z + v0.w + v1.x + v1.y + v1.z + v1.w;
        for (int o = 32; o; o >>= 1) s += __shfl_xor(s, o);
        if (lane == 0) sb1[wv] = s;
        __syncthreads();
        float mu = (sb1[0] + sb1[1] + sb1[2] + sb1[3]) * (1.0f / 2048.0f);
        float ssq = 0.f, md = 0.f, d;
        d = v0.x - mu; ssq += d * d; md = fmaxf(md, fabsf(d));
        d = v0.y - mu; ssq += d * d; md = fmaxf(md, fabsf(d));
        d = v0.z - mu; ssq += d * d; md = fmaxf(md, fabsf(d));
        d = v0.w - mu; ssq += d * d; md = fmaxf(md, fabsf(d));
        d = v1.x - mu; ssq += d * d; md = fmaxf(md, fabsf(d));
        d = v1.y - mu; ssq += d * d; md = fmaxf(md, fabsf(d));
        d = v1.z - mu; ssq += d * d; md = fmaxf(md, fabsf(d));
        d = v1.w - mu; ssq += d * d; md = fmaxf(md, fabsf(d));
        for (int o = 32; o; o >>= 1) {
            ssq += __shfl_xor(ssq, o);
            md = fmaxf(md, __shfl_xor(md, o));
        }
        if (lane == 0) { sb2[wv] = ssq; sb2[4 + wv] = md; }
        __syncthreads();
        if (t == 0) {
            float var = (sb2[0] + sb2[1] + sb2[2] + sb2[3]) * (1.0f / 2048.0f);
            float rstd = 1.0f / sqrtf(var + 1e-5f);
            mu_arr[row] = mu;
            rstd_arr[row] = rstd;
            rowmax[row] = fmaxf(fmaxf(sb2[4], sb2[5]), fmaxf(sb2[6], sb2[7])) * rstd;
        }
    }
}

// ---- wred2: finalize wmean/beta + global absmax ----
__global__ __launch_bounds__(256) void wred2(const double2* __restrict__ part,
                                             const float* __restrict__ rowmax,
                                             unsigned* __restrict__ scal) {
    double s = 0.0, a = 0.0;
    float m = 0.f;
    const int t = threadIdx.x, lane = t & 63, wv = t >> 6;
    for (int i = t; i < 1024; i += 256) { double2 p = part[i]; s += p.x; a += p.y; }
    for (int i = t; i < 8192; i += 256) m = fmaxf(m, rowmax[i]);
    for (int o = 32; o; o >>= 1) {
        s += __shfl_xor(s, o); a += __shfl_xor(a, o);
        m = fmaxf(m, __shfl_xor(m, o));
    }
    __shared__ double sbd[8];
    __shared__ float sbm[4];
    if (lane == 0) { sbd[wv] = s; sbd[4 + wv] = a; sbm[wv] = m; }
    __syncthreads();
    if (t == 0) {
        double st = sbd[0] + sbd[1] + sbd[2] + sbd[3];
        double at = sbd[4] + sbd[5] + sbd[6] + sbd[7];
        ((float*)scal)[0] = fmaxf(fmaxf(sbm[0], sbm[1]), fmaxf(sbm[2], sbm[3]));
        ((float*)scal)[1] = (float)(st / (double)NELEM_W);  // wmean
        ((float*)scal)[2] = (float)(at / (double)NELEM_W);  // beta
    }
}

// ---- fused pass2: quant_w (blocks 0..1023) + quant_x (1024..9215) ----
__device__ __forceinline__ int sgn8(float d) { return (d > 0.f) ? 1 : ((d < 0.f) ? -1 : 0); }

__global__ __launch_bounds__(256) void pass2(const float* __restrict__ x,
                                             const float4* __restrict__ w4,
                                             const float* __restrict__ mu_arr,
                                             const float* __restrict__ rstd_arr,
                                             const unsigned* __restrict__ scal,
                                             signed char* __restrict__ q,
                                             int4* __restrict__ wq4) {
    const int bid = blockIdx.x, t = threadIdx.x;
    if (bid < 1024) {
        float wm = ((const float*)scal)[1];
        for (int i = bid * 256 + t; i < NELEM_W / 16; i += 1024 * 256) {
            int words[4];
            #pragma unroll
            for (int jj = 0; jj < 4; ++jj) {
                float4 v = w4[i * 4 + jj];
                int b0 = sgn8(v.x - wm) & 255, b1 = sgn8(v.y - wm) & 255;
                int b2 = sgn8(v.z - wm) & 255, b3 = sgn8(v.w - wm) & 255;
                words[jj] = b0 | (b1 << 8) | (b2 << 16) | (b3 << 24);
            }
            wq4[i] = make_int4(words[0], words[1], words[2], words[3]);
        }
    } else {
        const int row = bid - 1024;
        float mu = mu_arr[row], rstd = rstd_arr[row];
        float s = 128.0f / ((const float*)scal)[0];
        const float4* xr = (const float4*)x + (size_t)row * 512;
        float4 v0 = xr[2 * t], v1 = xr[2 * t + 1];
        float xs[8] = {v0.x, v0.y, v0.z, v0.w, v1.x, v1.y, v1.z, v1.w};
        int b[8];
        #pragma unroll
        for (int j = 0; j < 8; ++j) {
            float norm = (xs[j] - mu) * rstd;
            int qi = (int)rintf(norm * s);   // half-even == jnp.round; +128 wraps via &255
            b[j] = qi & 255;
        }
        int w0 = b[0] | (b[1] << 8) | (b[2] << 16) | (b[3] << 24);
        int w1 = b[4] | (b[5] << 8) | (b[6] << 16) | (b[7] << 24);
        ((int2*)(q + (size_t)row * 2048))[t] = make_int2(w0, w1);
    }
}

// ---- int8 GEMM v14: fine-interleaved 4-phase schedule, 4-slab rotation ----
// 256x256 tile, BK=128 (2 K-slabs of 64), 8 waves (2Mx4N), wave 128x64 via
// mfma_i32_16x16x64 (8x4 frags, acc 128 VGPR). LDS = 4 slabs x 32KB = 128KB,
// 1 block/CU. Slab s -> buffer s&3; K-offset (s>>1)*128 + (s&1)*64.
// Per K-tile kt (slabs 2k, 2k+1), 4 phases:
//  P0: reads slab2k (m0-3 + B kk0) ; vmcnt(4) confirms slab2k+1 ; bar ; 16 MFMA ; bar
//  P1: issue slab2k+3 ; reads slab2k+1 (m0-3 + B kk1) ; bar ; 16 MFMA ; bar
//  P2: reads slab2k (m4-7; B reused) ; bar ; 16 MFMA ; bar
//  P3: issue slab2k+4 ; reads slab2k+1 (m4-7) ; vmcnt(8) confirms slab2k+2 ; bar ; MFMA ; bar
// In-flight 8-12 loads always (never <4). Issue overlaps MFMA phases (m196 lever).
// Buffer safety: slab s+4 write issued only after slab s's last-read trailing barrier.
#define LD16(p) (*(const i32x4*)(p))

#define ISSUE_SLAB(s)                                                                       \
    do {                                                                                    \
        const int bb_ = ((s) & 3) * 32768;                                                  \
        const int ko_ = ((s) >> 1) * 128 + ((s) & 1) * 64;                                  \
        __builtin_amdgcn_global_load_lds((cg_void*)(gA + ko_),                              \
            (lds_void*)(lds + bb_ + w * 2048), 16, 0, 0);                                   \
        __builtin_amdgcn_global_load_lds((cg_void*)(gA + 16 * K_DIM + ko_),                 \
            (lds_void*)(lds + bb_ + w * 2048 + 1024), 16, 0, 0);                            \
        __builtin_amdgcn_global_load_lds((cg_void*)(gB + ko_),                              \
            (lds_void*)(lds + bb_ + 16384 + w * 2048), 16, 0, 0);                           \
        __builtin_amdgcn_global_load_lds((cg_void*)(gB + 16 * K_DIM + ko_),                 \
            (lds_void*)(lds + bb_ + 16384 + w * 2048 + 1024), 16, 0, 0);                    \
    } while (0)

#define MF16(MB, AF, BF)                                                                    \
    __builtin_amdgcn_s_setprio(1);                                                          \
    _Pragma("unroll") for (int mm = 0; mm < 4; ++mm)                                        \
        _Pragma("unroll") for (int nn = 0; nn < 4; ++nn)                                    \
            acc[(MB) + mm][nn] = __builtin_amdgcn_mfma_i32_16x16x64_i8(                     \
                AF[mm], BF[nn], acc[(MB) + mm][nn], 0, 0, 0);                               \
    __builtin_amdgcn_s_setprio(0);

#define BAR() __builtin_amdgcn_s_barrier()
#define LGKM0() asm volatile("s_waitcnt lgkmcnt(0)" ::: "memory")

__global__ __launch_bounds__(512, 2) void gemm_i8(const signed char* __restrict__ A,
                                                  const signed char* __restrict__ B,
                                                  const float* __restrict__ bias,
                                                  const unsigned* __restrict__ scal,
                                                  float* __restrict__ C) {
    __shared__ alignas(16) char lds[131072];   // 4 slabs x 32KB
    const int t = threadIdx.x, w = t >> 6, lane = t & 63;

    // grid 1024 = 8 XCD x (4 m-panels x 32 n); A panel (512 KB) stays L2-hot per XCD.
    const int wg = blockIdx.x;
    const int xcd = wg & 7, idx = wg >> 3;
    const int bm = (xcd * 4 + (idx >> 5)) * 256;
    const int bn = (idx & 31) * 256;

    const int wr = w >> 2, wc = w & 3;         // wave grid 2M x 4N, wave tile 128x64
    const int r16 = lane & 15, ko = lane >> 4; // 16x16 fragment coords

    // staging: thread stages 16B; LDS dest wave-linear (1KB chunks of 16 rows); global
    // source col carries the involution col ^ (((lane>>3)&3)<<4)  [r6 pattern]
    const int srow = lane >> 2;
    const int scol = ((lane & 3) ^ ((lane >> 3) & 3)) << 4;
    const signed char* gA = A + (size_t)(bm + w * 32 + srow) * K_DIM + scol;
    const signed char* gB = B + (size_t)(bn + w * 32 + srow) * K_DIM + scol;

    // fragment reads: A row = wr*128 + mb*16 + r16; B row = wc*64 + nb*16 + r16;
    // 64B LDS rows; byte off = (ko*16) ^ (((r16>>1)&3)<<4)
    const char* aBase = lds + (wr * 128 + r16) * 64;
    const char* bBase = lds + 16384 + (wc * 64 + r16) * 64;
    const int sw = (ko * 16) ^ (((r16 >> 1) & 3) << 4);

    const float scale = (((const float*)scal)[0] * (1.0f / 128.0f)) * ((const float*)scal)[2];

    i32x4 acc[8][4] = {};
    i32x4 a0[4], a1[4], b0[4], b1[4];

    // prologue: slabs 0,1,2 issued (12 per-wave loads); confirm slab 0
    ISSUE_SLAB(0);
    ISSUE_SLAB(1);
    ISSUE_SLAB(2);
    asm volatile("s_waitcnt vmcnt(8)" ::: "memory");
    BAR();

    for (int kt = 0; kt < 16; ++kt) {
        const int c0 = ((2 * kt) & 3) * 32768;       // slab 2k buffer (kk0)
        const int c1 = ((2 * kt + 1) & 3) * 32768;   // slab 2k+1 buffer (kk1)

        // ---- P0: m0-3 x kk0 (slab 2k confirmed at prev P3) ----
        #pragma unroll
        for (int mb = 0; mb < 4; ++mb) a0[mb] = LD16(aBase + c0 + mb * 1024 + sw);
        #pragma unroll
        for (int nb = 0; nb < 4; ++nb) b0[nb] = LD16(bBase + c0 + nb * 1024 + sw);
        if (kt == 15) asm volatile("s_waitcnt vmcnt(0)" ::: "memory");
        else          asm volatile("s_waitcnt vmcnt(4)" ::: "memory");  // slab 2k+1 landed
        BAR();
        LGKM0();
        MF16(0, a0, b0);
        BAR();

        // ---- P1: m0-3 x kk1 ----
        if (kt <= 14) ISSUE_SLAB(2 * kt + 3);
        #pragma unroll
        for (int mb = 0; mb < 4; ++mb) a1[mb] = LD16(aBase + c1 + mb * 1024 + sw);
        #pragma unroll
        for (int nb = 0; nb < 4; ++nb) b1[nb] = LD16(bBase + c1 + nb * 1024 + sw);
        BAR();
        LGKM0();
        MF16(0, a1, b1);
        BAR();

        // ---- P2: m4-7 x kk0 (B kk0 reused) ----
        #pragma unroll
        for (int mb = 0; mb < 4; ++mb) a0[mb] = LD16(aBase + c0 + (4 + mb) * 1024 + sw);
        BAR();
        LGKM0();
        MF16(4, a0, b0);
        BAR();

        // ---- P3: m4-7 x kk1; confirm slab 2k+2 for next P0 ----
        if (kt <= 13) ISSUE_SLAB(2 * kt + 4);
        #pragma unroll
        for (int mb = 0; mb < 4; ++mb) a1[mb] = LD16(aBase + c1 + (4 + mb) * 1024 + sw);
        if (kt <= 13)      asm volatile("s_waitcnt vmcnt(8)" ::: "memory");
        else if (kt == 14) asm volatile("s_waitcnt vmcnt(4)" ::: "memory");
        BAR();
        LGKM0();
        MF16(4, a1, b1);
        BAR();
    }

    const int colbase = bn + wc * 64;
    float bi[4];
    #pragma unroll
    for (int nb = 0; nb < 4; ++nb) bi[nb] = bias[colbase + nb * 16 + r16];
    #pragma unroll
    for (int mb = 0; mb < 8; ++mb) {
        #pragma unroll
        for (int nb = 0; nb < 4; ++nb) {
            #pragma unroll
            for (int r = 0; r < 4; ++r) {
                // C/D 16x16: col = lane&15, row = (lane>>4)*4 + reg
                int row = bm + wr * 128 + mb * 16 + ko * 4 + r;
                int col = colbase + nb * 16 + r16;
                C[(size_t)row * N_DIM + col] = (float)acc[mb][nb][r] * scale + bi[nb];
            }
        }
    }
}

extern "C" void kernel_launch(void* const* d_in, const int* in_sizes, int n_in,
                              void* d_out, int out_size, void* d_ws, size_t ws_size,
                              hipStream_t stream) {
    const float* x = (const float*)d_in[0];
    const float* wts = (const float*)d_in[1];
    const float* bias = (const float*)d_in[2];
    float* out = (float*)d_out;

    char* ws = (char*)d_ws;
    unsigned* scal = (unsigned*)ws;                       // 64 B
    double2* part = (double2*)(ws + 1024);                // 16 KB
    float* mu = (float*)(ws + 32768);                     // 32 KB
    float* rstd = (float*)(ws + 65536);                   // 32 KB
    float* rowmax = (float*)(ws + 98304);                 // 32 KB
    signed char* q = (signed char*)(ws + 131072);         // 16 MB
    signed char* wq = (signed char*)(ws + 131072 + 16777216);  // 16 MB

    hipLaunchKernelGGL(pass1, dim3(9216), dim3(256), 0, stream,
                       x, (const float4*)wts, mu, rstd, rowmax, part);
    hipLaunchKernelGGL(wred2, dim3(1), dim3(256), 0, stream, part, rowmax, scal);
    hipLaunchKernelGGL(pass2, dim3(9216), dim3(256), 0, stream,
                       x, (const float4*)wts, mu, rstd, scal, q, (int4*)wq);
    hipLaunchKernelGGL(gemm_i8, dim3(1024), dim3(512), 0, stream,
                       q, wq, bias, scal, out);
}

// Round 15
// 228.226 us; speedup vs baseline: 1.0358x; 1.0182x over previous
//
#include <hip/hip_runtime.h>

// BitLinear: LN (no affine) -> global absmax int8 quant -> q @ sign(W-mean(W))^T
//   -> * (maxval/128 * mean|W|) + bias
// x: [4,2048,2048] f32 -> M=8192,K=2048 ; W: [8192,2048] -> N=8192 ; out f32 [8192,8192]

using i32x4 = __attribute__((ext_vector_type(4))) int;
using i32x16 = __attribute__((ext_vector_type(16))) int;

typedef const __attribute__((address_space(1))) void cg_void;
typedef __attribute__((address_space(3))) void lds_void;

#define K_DIM 2048
#define N_DIM 8192
#define M_DIM 8192
#define NELEM_W 16777216   // 8192*2048

// ws layout: scal@0 ([0]=absmax f32, [1]=wmean, [2]=beta); part@1024; mu@32768;
//            rstd@65536; rowmax@98304; q@131072; wq@131072+16M

// ---- fused pass1: W sum/abs-sum partials (blocks 0..1023) + LN stats (1024..9215) ----
__global__ __launch_bounds__(256) void pass1(const float* __restrict__ x,
                                             const float4* __restrict__ w4,
                                             float* __restrict__ mu_arr,
                                             float* __restrict__ rstd_arr,
                                             float* __restrict__ rowmax,
                                             double2* __restrict__ part) {
    __shared__ double sbd[8];
    __shared__ float sb1[4];
    __shared__ float sb2[8];
    const int bid = blockIdx.x, t = threadIdx.x;
    const int lane = t & 63, wv = t >> 6;
    if (bid < 1024) {
        double s = 0.0, a = 0.0;
        for (int i = bid * 256 + t; i < NELEM_W / 4; i += 1024 * 256) {
            float4 v = w4[i];
            s += (double)v.x + (double)v.y + (double)v.z + (double)v.w;
            a += fabs((double)v.x) + fabs((double)v.y) + fabs((double)v.z) + fabs((double)v.w);
        }
        for (int o = 32; o; o >>= 1) { s += __shfl_xor(s, o); a += __shfl_xor(a, o); }
        if (lane == 0) { sbd[wv] = s; sbd[4 + wv] = a; }
        __syncthreads();
        if (t == 0) {
            double2 r;
            r.x = sbd[0] + sbd[1] + sbd[2] + sbd[3];
            r.y = sbd[4] + sbd[5] + sbd[6] + sbd[7];
            part[bid] = r;
        }
    } else {
        const int row = bid - 1024;
        const float4* xr = (const float4*)x + (size_t)row * 512;
        float4 v0 = xr[t], v1 = xr[t + 256];
        float s = v0.x + v0.y + v0.z + v0.w + v1.x + v1.y + v1.z + v1.w;
        for (int o = 32; o; o >>= 1) s += __shfl_xor(s, o);
        if (lane == 0) sb1[wv] = s;
        __syncthreads();
        float mu = (sb1[0] + sb1[1] + sb1[2] + sb1[3]) * (1.0f / 2048.0f);
        float ssq = 0.f, md = 0.f, d;
        d = v0.x - mu; ssq += d * d; md = fmaxf(md, fabsf(d));
        d = v0.y - mu; ssq += d * d; md = fmaxf(md, fabsf(d));
        d = v0.z - mu; ssq += d * d; md = fmaxf(md, fabsf(d));
        d = v0.w - mu; ssq += d * d; md = fmaxf(md, fabsf(d));
        d = v1.x - mu; ssq += d * d; md = fmaxf(md, fabsf(d));
        d = v1.y - mu; ssq += d * d; md = fmaxf(md, fabsf(d));
        d = v1.z - mu; ssq += d * d; md = fmaxf(md, fabsf(d));
        d = v1.w - mu; ssq += d * d; md = fmaxf(md, fabsf(d));
        for (int o = 32; o; o >>= 1) {
            ssq += __shfl_xor(ssq, o);
            md = fmaxf(md, __shfl_xor(md, o));
        }
        if (lane == 0) { sb2[wv] = ssq; sb2[4 + wv] = md; }
        __syncthreads();
        if (t == 0) {
            float var = (sb2[0] + sb2[1] + sb2[2] + sb2[3]) * (1.0f / 2048.0f);
            float rstd = 1.0f / sqrtf(var + 1e-5f);
            mu_arr[row] = mu;
            rstd_arr[row] = rstd;
            rowmax[row] = fmaxf(fmaxf(sb2[4], sb2[5]), fmaxf(sb2[6], sb2[7])) * rstd;
        }
    }
}

// ---- wred2: finalize wmean/beta + global absmax ----
__global__ __launch_bounds__(256) void wred2(const double2* __restrict__ part,
                                             const float* __restrict__ rowmax,
                                             unsigned* __restrict__ scal) {
    double s = 0.0, a = 0.0;
    float m = 0.f;
    const int t = threadIdx.x, lane = t & 63, wv = t >> 6;
    for (int i = t; i < 1024; i += 256) { double2 p = part[i]; s += p.x; a += p.y; }
    for (int i = t; i < 8192; i += 256) m = fmaxf(m, rowmax[i]);
    for (int o = 32; o; o >>= 1) {
        s += __shfl_xor(s, o); a += __shfl_xor(a, o);
        m = fmaxf(m, __shfl_xor(m, o));
    }
    __shared__ double sbd[8];
    __shared__ float sbm[4];
    if (lane == 0) { sbd[wv] = s; sbd[4 + wv] = a; sbm[wv] = m; }
    __syncthreads();
    if (t == 0) {
        double st = sbd[0] + sbd[1] + sbd[2] + sbd[3];
        double at = sbd[4] + sbd[5] + sbd[6] + sbd[7];
        ((float*)scal)[0] = fmaxf(fmaxf(sbm[0], sbm[1]), fmaxf(sbm[2], sbm[3]));
        ((float*)scal)[1] = (float)(st / (double)NELEM_W);  // wmean
        ((float*)scal)[2] = (float)(at / (double)NELEM_W);  // beta
    }
}

// ---- fused pass2: quant_w (blocks 0..1023) + quant_x (1024..9215) ----
__device__ __forceinline__ int sgn8(float d) { return (d > 0.f) ? 1 : ((d < 0.f) ? -1 : 0); }

__global__ __launch_bounds__(256) void pass2(const float* __restrict__ x,
                                             const float4* __restrict__ w4,
                                             const float* __restrict__ mu_arr,
                                             const float* __restrict__ rstd_arr,
                                             const unsigned* __restrict__ scal,
                                             signed char* __restrict__ q,
                                             int4* __restrict__ wq4) {
    const int bid = blockIdx.x, t = threadIdx.x;
    if (bid < 1024) {
        float wm = ((const float*)scal)[1];
        for (int i = bid * 256 + t; i < NELEM_W / 16; i += 1024 * 256) {
            int words[4];
            #pragma unroll
            for (int jj = 0; jj < 4; ++jj) {
                float4 v = w4[i * 4 + jj];
                int b0 = sgn8(v.x - wm) & 255, b1 = sgn8(v.y - wm) & 255;
                int b2 = sgn8(v.z - wm) & 255, b3 = sgn8(v.w - wm) & 255;
                words[jj] = b0 | (b1 << 8) | (b2 << 16) | (b3 << 24);
            }
            wq4[i] = make_int4(words[0], words[1], words[2], words[3]);
        }
    } else {
        const int row = bid - 1024;
        float mu = mu_arr[row], rstd = rstd_arr[row];
        float s = 128.0f / ((const float*)scal)[0];
        const float4* xr = (const float4*)x + (size_t)row * 512;
        float4 v0 = xr[2 * t], v1 = xr[2 * t + 1];
        float xs[8] = {v0.x, v0.y, v0.z, v0.w, v1.x, v1.y, v1.z, v1.w};
        int b[8];
        #pragma unroll
        for (int j = 0; j < 8; ++j) {
            float norm = (xs[j] - mu) * rstd;
            int qi = (int)rintf(norm * s);   // half-even == jnp.round; +128 wraps via &255
            b[j] = qi & 255;
        }
        int w0 = b[0] | (b[1] << 8) | (b[2] << 16) | (b[3] << 24);
        int w1 = b[4] | (b[5] << 8) | (b[6] << 16) | (b[7] << 24);
        ((int2*)(q + (size_t)row * 2048))[t] = make_int2(w0, w1);
    }
}

// ---- int8 GEMM (champion config, r6): 256x128 tile, BK=64, 8 waves (4Mx2N), ----
// 48KB LDS -> 2 blocks/CU. Per-wave 64x64 = 2x2 of 32x32x32 (64 acc VGPR).
// Two independent barrier groups per CU phase-offset naturally: one block's MFMA
// covers the other's ds_read/DMA bursts (measured optimum of the blocks/CU axis:
// 8 groups=194us, 2 groups=173us, 1 group=184us). Involution swizzle
// col ^ (((row>>1)&3)<<4) source-side (4cyc/read residual conflict tax measured
// non-binding in r10). Staging 3 gloads/thread/tile, counted vmcnt(3).
#define LD16(p) (*(const i32x4*)(p))
#define TILE_BYTES 24576   // A 16K + B 8K per buffer

#define STAGE(koff, sbase)                                                                  \
    do {                                                                                    \
        __builtin_amdgcn_global_load_lds((cg_void*)(gA + (koff)),                           \
            (lds_void*)(lds + (sbase) + w * 2048), 16, 0, 0);                               \
        __builtin_amdgcn_global_load_lds((cg_void*)(gA + 16 * K_DIM + (koff)),              \
            (lds_void*)(lds + (sbase) + w * 2048 + 1024), 16, 0, 0);                        \
        __builtin_amdgcn_global_load_lds((cg_void*)(gB + (koff)),                           \
            (lds_void*)(lds + (sbase) + 16384 + w * 1024), 16, 0, 0);                       \
    } while (0)

__global__ __launch_bounds__(512, 4) void gemm_i8(const signed char* __restrict__ A,
                                                  const signed char* __restrict__ B,
                                                  const float* __restrict__ bias,
                                                  const unsigned* __restrict__ scal,
                                                  float* __restrict__ C) {
    __shared__ alignas(16) char lds[49152];    // 2 x (A 16K + B 8K)
    const int t = threadIdx.x, w = t >> 6, lane = t & 63;

    // grid 2048 = 8 XCD x (4 m-panels x 64 n); contiguous n per m keeps the 512 KB
    // A panel L2-hot; quantized B (16 MB) is L3-resident.
    const int wg = blockIdx.x;
    const int xcd = wg & 7, idx = wg >> 3;
    const int bm = (xcd * 4 + (idx >> 6)) * 256;
    const int bn = (idx & 63) * 128;

    const int wr = w >> 1, wc = w & 1;         // wave grid 4M x 2N
    const int r32 = lane & 31, hi = lane >> 5; // 32x32 fragment coords

    // staging: thread stages 16B at linear chunk*1024 + lane*16 -> row = chunk*16 +
    // (lane>>2), lds col = (lane&3)*16; source col ^= ((row>>1)&3)<<4 = ((lane>>3)&3)<<4
    const int srow = lane >> 2;
    const int scol = ((lane & 3) ^ ((lane >> 3) & 3)) << 4;
    const signed char* gA = A + (size_t)(bm + w * 32 + srow) * K_DIM + scol;
    const signed char* gB = B + (size_t)(bn + w * 16 + srow) * K_DIM + scol;

    // fragment reads (swizzled): A row = wr*64 + mb*32 + r32; B row = wc*64 + nb*32 + r32
    const char* aBase = lds + (wr * 64 + r32) * 64;
    const char* bBase = lds + 16384 + (wc * 64 + r32) * 64;
    const int swz = ((r32 >> 1) & 3) << 4;
    const int sw0 = (hi * 16) ^ swz;           // kstep 0
    const int sw1 = (32 + hi * 16) ^ swz;      // kstep 1

    const float scale = (((const float*)scal)[0] * (1.0f / 128.0f)) * ((const float*)scal)[2];

    i32x16 acc[2][2] = {};
    i32x4 a0[2], a1[2], b0[2], b1[2];

    STAGE(0, 0);   // prologue: tile 0 -> buf0 (3 loads in flight)

    #pragma unroll 2
    for (int kt = 0; kt < 32; ++kt) {
        const int c = (kt & 1) * TILE_BYTES;
        if (kt < 31) {
            STAGE((kt + 1) * 64, ((kt + 1) & 1) * TILE_BYTES);
            asm volatile("s_waitcnt vmcnt(3)" ::: "memory");  // this tile's 3 landed
        } else {
            asm volatile("s_waitcnt vmcnt(0)" ::: "memory");
        }
        __builtin_amdgcn_s_barrier();          // buf c ready

        #pragma unroll
        for (int mb = 0; mb < 2; ++mb) a0[mb] = LD16(aBase + c + mb * 2048 + sw0);
        #pragma unroll
        for (int nb = 0; nb < 2; ++nb) b0[nb] = LD16(bBase + c + nb * 2048 + sw0);
        #pragma unroll
        for (int mb = 0; mb < 2; ++mb) a1[mb] = LD16(aBase + c + mb * 2048 + sw1);
        #pragma unroll
        for (int nb = 0; nb < 2; ++nb) b1[nb] = LD16(bBase + c + nb * 2048 + sw1);
        __builtin_amdgcn_s_setprio(1);
        #pragma unroll
        for (int mb = 0; mb < 2; ++mb)
            #pragma unroll
            for (int nb = 0; nb < 2; ++nb)
                acc[mb][nb] = __builtin_amdgcn_mfma_i32_32x32x32_i8(a0[mb], b0[nb],
                                                                    acc[mb][nb], 0, 0, 0);
        #pragma unroll
        for (int mb = 0; mb < 2; ++mb)
            #pragma unroll
            for (int nb = 0; nb < 2; ++nb)
                acc[mb][nb] = __builtin_amdgcn_mfma_i32_32x32x32_i8(a1[mb], b1[nb],
                                                                    acc[mb][nb], 0, 0, 0);
        __builtin_amdgcn_s_setprio(0);
        __builtin_amdgcn_s_barrier();          // all waves done reading buf c
    }

    const int colbase = bn + wc * 64;
    float bi[2];
    #pragma unroll
    for (int nb = 0; nb < 2; ++nb) bi[nb] = bias[colbase + nb * 32 + r32];
    #pragma unroll
    for (int mb = 0; mb < 2; ++mb) {
        #pragma unroll
        for (int nb = 0; nb < 2; ++nb) {
            #pragma unroll
            for (int r = 0; r < 16; ++r) {
                // C/D 32x32: col = lane&31, row = (r&3) + 8*(r>>2) + 4*(lane>>5)
                int row = bm + wr * 64 + mb * 32 + (r & 3) + 8 * (r >> 2) + 4 * hi;
                int col = colbase + nb * 32 + r32;
                C[(size_t)row * N_DIM + col] = (float)acc[mb][nb][r] * scale + bi[nb];
            }
        }
    }
}

extern "C" void kernel_launch(void* const* d_in, const int* in_sizes, int n_in,
                              void* d_out, int out_size, void* d_ws, size_t ws_size,
                              hipStream_t stream) {
    const float* x = (const float*)d_in[0];
    const float* wts = (const float*)d_in[1];
    const float* bias = (const float*)d_in[2];
    float* out = (float*)d_out;

    char* ws = (char*)d_ws;
    unsigned* scal = (unsigned*)ws;                       // 64 B
    double2* part = (double2*)(ws + 1024);                // 16 KB
    float* mu = (float*)(ws + 32768);                     // 32 KB
    float* rstd = (float*)(ws + 65536);                   // 32 KB
    float* rowmax = (float*)(ws + 98304);                 // 32 KB
    signed char* q = (signed char*)(ws + 131072);         // 16 MB
    signed char* wq = (signed char*)(ws + 131072 + 16777216);  // 16 MB

    hipLaunchKernelGGL(pass1, dim3(9216), dim3(256), 0, stream,
                       x, (const float4*)wts, mu, rstd, rowmax, part);
    hipLaunchKernelGGL(wred2, dim3(1), dim3(256), 0, stream, part, rowmax, scal);
    hipLaunchKernelGGL(pass2, dim3(9216), dim3(256), 0, stream,
                       x, (const float4*)wts, mu, rstd, scal, q, (int4*)wq);
    hipLaunchKernelGGL(gemm_i8, dim3(2048), dim3(512), 0, stream,
                       q, wq, bias, scal, out);
}